// Round 6
// baseline (1632.899 us; speedup 1.0000x reference)
//
#include <hip/hip_runtime.h>
#include <hip/hip_bf16.h>

typedef __attribute__((ext_vector_type(4))) float f32x4;
typedef __attribute__((ext_vector_type(8))) short bf16x8;   // MFMA 16x16x32 A/B operand
typedef __attribute__((ext_vector_type(4))) int   i32x4;
typedef __attribute__((ext_vector_type(2))) int   i32x2;

#define QK_SCALE 0.04419417382415922f   // 512^-0.5

static __device__ __forceinline__ unsigned short f2bf(float f) {
    unsigned int u = __builtin_bit_cast(unsigned int, f);
    u += 0x7fffu + ((u >> 16) & 1u);          // RNE
    return (unsigned short)(u >> 16);
}
static __device__ __forceinline__ float bf2f(unsigned short h) {
    unsigned int u = ((unsigned int)h) << 16;
    return __builtin_bit_cast(float, u);
}
static __device__ __forceinline__ f32x4 fzero() {
    f32x4 v; v[0] = 0.f; v[1] = 0.f; v[2] = 0.f; v[3] = 0.f; return v;
}
static __device__ __forceinline__ int pack2(float a, float b) {
    return (int)((((unsigned)f2bf(b)) << 16) | f2bf(a));
}

// ---------------------------------------------------------------------------
// kw_weights: W'[0:512]   = (wq^T wk) * gamma[c] * QK_SCALE   (G weights)
//             W'[512:1024]= (wproj wv) * gamma[c]             (U weights)
// rsW[o] = sum_c W'[o][c];  bW[o] = scale * sum_c W0[o][c]*beta[c]
// ---------------------------------------------------------------------------
__global__ __launch_bounds__(256) void kw_weights(
    const float* __restrict__ wq, const float* __restrict__ wk,
    const float* __restrict__ wproj, const float* __restrict__ wv,
    const float* __restrict__ gamma, const float* __restrict__ beta,
    unsigned short* __restrict__ Wp, float* __restrict__ rsW, float* __restrict__ bW)
{
    int bx = blockIdx.x;            // 128 blocks: [0,64) -> G, [64,128) -> U
    int mat = bx >> 6;
    int tile = bx & 63;
    int i0 = (tile >> 3) * 64, j0 = (tile & 7) * 64;
    const float* A  = mat ? wproj : wq;
    const float* Bm = mat ? wv : wk;
    __shared__ float At[16][64];
    __shared__ float Bt[16][64];
    int tid = threadIdx.x;
    int ty = tid >> 4, tx = tid & 15;
    float acc[4][4] = {};
    for (int k0 = 0; k0 < 512; k0 += 16) {
        if (mat == 0) {
            // At[kk][ii] = wq[k0+kk][i0+ii]   (wq^T form)
#pragma unroll
            for (int r = 0; r < 4; ++r) {
                int idx = r * 256 + tid;
                At[idx >> 6][idx & 63] = A[(size_t)(k0 + (idx >> 6)) * 512 + i0 + (idx & 63)];
            }
        } else {
            // At[kk][ii] = wproj[i0+ii][k0+kk]
#pragma unroll
            for (int r = 0; r < 4; ++r) {
                int idx = r * 256 + tid;
                At[idx & 15][idx >> 4] = A[(size_t)(i0 + (idx >> 4)) * 512 + k0 + (idx & 15)];
            }
        }
#pragma unroll
        for (int r = 0; r < 4; ++r) {
            int idx = r * 256 + tid;
            Bt[idx >> 6][idx & 63] = Bm[(size_t)(k0 + (idx >> 6)) * 512 + j0 + (idx & 63)];
        }
        __syncthreads();
#pragma unroll
        for (int kk = 0; kk < 16; ++kk)
#pragma unroll
            for (int i = 0; i < 4; ++i)
#pragma unroll
                for (int j = 0; j < 4; ++j)
                    acc[i][j] += At[kk][ty * 4 + i] * Bt[kk][tx * 4 + j];
        __syncthreads();
    }
    float sc = mat ? 1.0f : QK_SCALE;
#pragma unroll
    for (int i = 0; i < 4; ++i) {
        int o = mat * 512 + i0 + ty * 4 + i;
        float rsum = 0.f, bsum = 0.f;
        ushort4 pk;
        unsigned short e[4];
#pragma unroll
        for (int j = 0; j < 4; ++j) {
            int c = j0 + tx * 4 + j;
            float w0 = acc[i][j] * sc;
            float wg = w0 * gamma[c];
            rsum += wg;
            bsum += w0 * beta[c];
            e[j] = f2bf(wg);
        }
        pk.x = e[0]; pk.y = e[1]; pk.z = e[2]; pk.w = e[3];
        *(ushort4*)(Wp + (size_t)o * 512 + j0 + tx * 4) = pk;
        // reduce rsum/bsum across tx (16 lanes, same ty)
        rsum += __shfl_xor(rsum, 1); bsum += __shfl_xor(bsum, 1);
        rsum += __shfl_xor(rsum, 2); bsum += __shfl_xor(bsum, 2);
        rsum += __shfl_xor(rsum, 4); bsum += __shfl_xor(bsum, 4);
        rsum += __shfl_xor(rsum, 8); bsum += __shfl_xor(bsum, 8);
        if (tx == 0) { atomicAdd(&rsW[o], rsum); atomicAdd(&bW[o], bsum); }
    }
}

// ---------------------------------------------------------------------------
// k_transpose_stats: x[b][c][t][h][w] -> Hraw[pix][t][c] (raw bf16)
// + per-(b,t) partial sums (sum, sumsq) via atomics.
// ---------------------------------------------------------------------------
__global__ __launch_bounds__(512) void k_transpose_stats(
    const float* __restrict__ x, unsigned short* __restrict__ Hraw, float* __restrict__ sums)
{
    int bx = blockIdx.x;                  // 2048 = 4*32*16
    int tp = bx & 15;
    int h  = (bx >> 4) & 31;
    int bb = bx >> 9;
    int t0 = tp * 2;
    int tid = threadIdx.x;
    extern __shared__ char lds[];         // 64KB + 128B reduce scratch
    float* red = (float*)(lds + 65536);

    int tt = (tid >> 3) & 1;
    int w4 = tid & 7;
    int cb = tid >> 4;
    float s = 0.f, q = 0.f;
    const unsigned int Kt = (unsigned int)tt * 64u + (unsigned int)w4 * 8u;
#pragma unroll
    for (int it = 0; it < 16; ++it) {
        int c = it * 32 + cb;
        float4 v = *(const float4*)(x + (((size_t)(bb * 512 + c)) * 32 + (t0 + tt)) * 1024 + h * 32 + w4 * 4);
        s += v.x + v.y + v.z + v.w;
        q += v.x * v.x + v.y * v.y + v.z * v.z + v.w * v.w;
        unsigned int p0 = ((unsigned int)f2bf(v.y) << 16) | f2bf(v.x);
        unsigned int p1 = ((unsigned int)f2bf(v.w) << 16) | f2bf(v.z);
        unsigned int Kx = ((unsigned int)((c >> 3) & 31)) << 2;
        unsigned int base = (unsigned int)c * 128u + Kt;
        *(unsigned int*)(lds + ((base + 0u) ^ Kx)) = p0;
        *(unsigned int*)(lds + ((base + 4u) ^ Kx)) = p1;
    }
    s += __shfl_xor(s, 1);  q += __shfl_xor(q, 1);
    s += __shfl_xor(s, 2);  q += __shfl_xor(q, 2);
    s += __shfl_xor(s, 4);  q += __shfl_xor(q, 4);
    s += __shfl_xor(s, 16); q += __shfl_xor(q, 16);
    s += __shfl_xor(s, 32); q += __shfl_xor(q, 32);
    int wid = tid >> 6, lane = tid & 63;
    if (lane == 0) { red[wid * 4 + 0] = s; red[wid * 4 + 1] = q; }
    if (lane == 8) { red[wid * 4 + 2] = s; red[wid * 4 + 3] = q; }
    __syncthreads();
    if (tid < 4) {
        float a = 0.f;
#pragma unroll
        for (int w = 0; w < 8; ++w) a += red[w * 4 + tid];
        int f = bb * 32 + t0 + (tid >> 1);
        atomicAdd(&sums[f * 2 + (tid & 1)], a);
    }
#pragma unroll
    for (int rnd = 0; rnd < 8; ++rnd) {
        int row = rnd * 8 + wid;
        int w = row >> 1, ttw = row & 1;
        int c0 = lane * 8;
        unsigned short e[8];
#pragma unroll
        for (int j = 0; j < 8; ++j) {
            int c = c0 + j;
            unsigned int Kx = ((unsigned int)((c >> 3) & 31)) << 2;
            unsigned int off = ((unsigned int)(c * 128 + ttw * 64 + 2 * w)) ^ Kx;
            e[j] = *(const unsigned short*)(lds + off);
        }
        i32x4 ov;
        ov[0] = (int)(((unsigned int)e[1] << 16) | e[0]);
        ov[1] = (int)(((unsigned int)e[3] << 16) | e[2]);
        ov[2] = (int)(((unsigned int)e[5] << 16) | e[4]);
        ov[3] = (int)(((unsigned int)e[7] << 16) | e[6]);
        size_t pix = ((size_t)bb * 32 + h) * 32 + w;
        *(i32x4*)(Hraw + pix * 16384 + (size_t)(t0 + ttw) * 512 + c0) = ov;
    }
}

// ---------------------------------------------------------------------------
__global__ void k_finalize(const float* __restrict__ sums, float* __restrict__ mr) {
    int f = threadIdx.x;                  // 128 frames
    float mean = sums[f * 2] * (1.f / 524288.f);
    float var  = sums[f * 2 + 1] * (1.f / 524288.f) - mean * mean;
    mr[f * 2]     = mean;
    mr[f * 2 + 1] = rsqrtf(var + 1e-6f);
}

// ---------------------------------------------------------------------------
// k_gemm: D[1024 o][131072 n] = W'[o][c] . Hraw[n][c]  (K=512), epilogue affine:
//   val = rs_n * (D - mu_n * rsW[o]) + bW[o]
// o<512  -> G[n][o]   (direct 8B stores; operands A=W,B=H)
// o>=512 -> UT[o-512][n] (direct 8B stores; operands swapped A=H,B=W)
// Tiles: BM=128 (8 mtiles), BN=256 (512 strips), BK=64 dbuf via global_load_lds.
// Grid swizzle co-locates a strip's 8 mtile-siblings on one XCD for L2 reuse.
// ---------------------------------------------------------------------------
__global__ __launch_bounds__(512, 4) void k_gemm(
    const unsigned short* __restrict__ Hraw,
    const unsigned short* __restrict__ Wp,
    const float* __restrict__ rsW, const float* __restrict__ bW,
    const float* __restrict__ mr,
    unsigned short* __restrict__ G, unsigned short* __restrict__ UT)
{
    extern __shared__ char lds[];
    int d = blockIdx.x;
    int mtile = (d >> 3) & 7;
    int strip = (d & 7) | ((d >> 6) << 3);
    int n0 = strip * 256;
    int tid = threadIdx.x, wid = tid >> 6, lane = tid & 63;
    int lo = lane & 15, hi = lane >> 4;
    int o0w = mtile * 128 + (wid >> 2) * 64;
    int n0w = (wid & 3) * 64;
    bool isU = mtile >= 4;

    int srow = tid >> 3;                                    // 0..63
    unsigned scol = (((unsigned)(tid & 7)) * 16u) ^ ((((unsigned)srow) & 7u) << 4);

    f32x4 acc[4][4];
#pragma unroll
    for (int a = 0; a < 4; ++a)
#pragma unroll
        for (int b = 0; b < 4; ++b) acc[a][b] = fzero();

#define STAGE(bufi, kk)                                                                                   \
    {                                                                                                     \
        _Pragma("unroll")                                                                                 \
        for (int r = 0; r < 4; ++r) {                                                                     \
            const char* src = (const char*)Hraw + (size_t)(n0 + r * 64 + srow) * 1024 + (size_t)(kk) * 128 + scol; \
            char* dst = lds + (bufi) * 32768 + r * 8192 + wid * 1024;                                     \
            __builtin_amdgcn_global_load_lds((const __attribute__((address_space(1))) unsigned int*)src,  \
                                             (__attribute__((address_space(3))) unsigned int*)dst, 16, 0, 0); \
        }                                                                                                 \
    }

    STAGE(0, 0);
    __syncthreads();

    const unsigned short* wbase = Wp + (size_t)(o0w + lo) * 512 + hi * 8;
    int buf = 0;
    for (int k = 0; k < 8; ++k) {
        if (k < 7) STAGE(buf ^ 1, k + 1);
        const char* B = lds + buf * 32768;
#pragma unroll
        for (int half = 0; half < 2; ++half) {
            bf16x8 wa[4], hb[4];
#pragma unroll
            for (int mt = 0; mt < 4; ++mt)
                wa[mt] = *(const bf16x8*)(wbase + (size_t)mt * 16 * 512 + k * 64 + half * 32);
#pragma unroll
            for (int nt = 0; nt < 4; ++nt) {
                int n = n0w + nt * 16 + lo;
                unsigned off = (unsigned)(n * 128) + (((unsigned)(half * 64 + hi * 16)) ^ ((((unsigned)n) & 7u) << 4));
                hb[nt] = *(const bf16x8*)(B + off);
            }
            if (!isU) {
#pragma unroll
                for (int mt = 0; mt < 4; ++mt)
#pragma unroll
                    for (int nt = 0; nt < 4; ++nt)
                        acc[mt][nt] = __builtin_amdgcn_mfma_f32_16x16x32_bf16(wa[mt], hb[nt], acc[mt][nt], 0, 0, 0);
            } else {
#pragma unroll
                for (int mt = 0; mt < 4; ++mt)
#pragma unroll
                    for (int nt = 0; nt < 4; ++nt)
                        acc[mt][nt] = __builtin_amdgcn_mfma_f32_16x16x32_bf16(hb[nt], wa[mt], acc[mt][nt], 0, 0, 0);
            }
        }
        __syncthreads();
        buf ^= 1;
    }
#undef STAGE

    int n_base = n0 + n0w;
    if (!isU) {
        // D[o][n]: row(4hi+i)=o-rel, col(lo)=n-rel. Write G[n][o], 4 o-consecutive per lane.
#pragma unroll
        for (int nt = 0; nt < 4; ++nt) {
            int n = n_base + nt * 16 + lo;
            int f = ((n >> 15) << 5) | (n & 31);
            float2 mv = *(const float2*)(mr + f * 2);
#pragma unroll
            for (int mt = 0; mt < 4; ++mt) {
                int ob = o0w + mt * 16 + 4 * hi;
                f32x4 rw = *(const f32x4*)(rsW + ob);
                f32x4 bv = *(const f32x4*)(bW + ob);
                f32x4 a = acc[mt][nt];
                float v0 = mv.y * (a[0] - mv.x * rw[0]) + bv[0];
                float v1 = mv.y * (a[1] - mv.x * rw[1]) + bv[1];
                float v2 = mv.y * (a[2] - mv.x * rw[2]) + bv[2];
                float v3 = mv.y * (a[3] - mv.x * rw[3]) + bv[3];
                i32x2 pk; pk[0] = pack2(v0, v1); pk[1] = pack2(v2, v3);
                *(i32x2*)(G + (size_t)n * 512 + ob) = pk;
            }
        }
    } else {
        // D[n][o]: row(4hi+i)=n-rel, col(lo)=o-rel. Write UT[o-512][n], 4 n-consecutive per lane.
#pragma unroll
        for (int nt = 0; nt < 4; ++nt) {
            float2 mv[4];
#pragma unroll
            for (int i = 0; i < 4; ++i) {
                int n = n_base + nt * 16 + 4 * hi + i;
                int f = ((n >> 15) << 5) | (n & 31);
                mv[i] = *(const float2*)(mr + f * 2);
            }
            int ncol = n_base + nt * 16 + 4 * hi;
#pragma unroll
            for (int mt = 0; mt < 4; ++mt) {
                int o = o0w + mt * 16 + lo;          // 512..1023
                float rw = rsW[o], bv = bW[o];
                f32x4 a = acc[mt][nt];
                float v0 = mv[0].y * (a[0] - mv[0].x * rw) + bv;
                float v1 = mv[1].y * (a[1] - mv[1].x * rw) + bv;
                float v2 = mv[2].y * (a[2] - mv[2].x * rw) + bv;
                float v3 = mv[3].y * (a[3] - mv[3].x * rw) + bv;
                i32x2 pk; pk[0] = pack2(v0, v1); pk[1] = pack2(v2, v3);
                *(i32x2*)(UT + (size_t)(o - 512) * 131072 + ncol) = pk;
            }
        }
    }
}

// ---------------------------------------------------------------------------
// k_attn: 1 pixel per wave, 8 waves/block, no barriers.
// logits[t][s] = sum_c h[c,t] g[c,s]  (h = affine(Hraw) on the fly, A-frags;
// G rows as B-frags; causal tile [t<16][s>=16] skipped). In-register softmax.
// P staged in 2KB/wave LDS. PV: out[t][o] = P . UT-frags; OA written over Hraw.
// ---------------------------------------------------------------------------
__global__ __launch_bounds__(512, 4) void k_attn(
    const unsigned short* Hraw,
    const unsigned short* __restrict__ G,
    const unsigned short* __restrict__ UT,
    const float* __restrict__ gamma, const float* __restrict__ beta,
    const float* __restrict__ mr,
    unsigned short* OA)
{
    __shared__ char plds[16384];
    int tid = threadIdx.x, wid = tid >> 6, lane = tid & 63;
    int lo = lane & 15, hi = lane >> 4;
    int pix = blockIdx.x * 8 + wid;
    int b_ = pix >> 10;
    char* pb = plds + wid * 2048;

    // zero P region (masked slots must read as 0)
    {
        i32x4 z; z[0] = 0; z[1] = 0; z[2] = 0; z[3] = 0;
        *(i32x4*)(pb + lane * 32) = z;
        *(i32x4*)(pb + lane * 32 + 16) = z;
    }

    float2 q0 = *(const float2*)(mr + ((size_t)b_ * 32 + lo) * 2);        // t = lo
    float2 q1 = *(const float2*)(mr + ((size_t)b_ * 32 + 16 + lo) * 2);   // t = 16+lo

    const unsigned short* Hrow0 = Hraw + ((size_t)pix * 32 + lo) * 512;
    const unsigned short* Hrow1 = Hrow0 + 16 * 512;
    const unsigned short* Grow0 = G + ((size_t)pix * 32 + lo) * 512;
    const unsigned short* Grow1 = Grow0 + 16 * 512;

    f32x4 a00 = fzero(), a10 = fzero(), a11 = fzero();
#pragma unroll 2
    for (int c0 = 0; c0 < 512; c0 += 32) {
        int cb = c0 + hi * 8;
        f32x4 g0 = *(const f32x4*)(gamma + cb);
        f32x4 g1 = *(const f32x4*)(gamma + cb + 4);
        f32x4 b0 = *(const f32x4*)(beta + cb);
        f32x4 b1 = *(const f32x4*)(beta + cb + 4);
        bf16x8 r0 = *(const bf16x8*)(Hrow0 + cb);
        bf16x8 r1 = *(const bf16x8*)(Hrow1 + cb);
        bf16x8 gb0 = *(const bf16x8*)(Grow0 + cb);
        bf16x8 gb1 = *(const bf16x8*)(Grow1 + cb);
        bf16x8 h0, h1;
#pragma unroll
        for (int j = 0; j < 8; ++j) {
            float gg = (j < 4) ? g0[j] : g1[j - 4];
            float bb = (j < 4) ? b0[j] : b1[j - 4];
            float x0 = bf2f((unsigned short)r0[j]);
            float x1 = bf2f((unsigned short)r1[j]);
            h0[j] = (short)f2bf((x0 - q0.x) * (q0.y * gg) + bb);
            h1[j] = (short)f2bf((x1 - q1.x) * (q1.y * gg) + bb);
        }
        a00 = __builtin_amdgcn_mfma_f32_16x16x32_bf16(h0, gb0, a00, 0, 0, 0);
        a10 = __builtin_amdgcn_mfma_f32_16x16x32_bf16(h1, gb0, a10, 0, 0, 0);
        a11 = __builtin_amdgcn_mfma_f32_16x16x32_bf16(h1, gb1, a11, 0, 0, 0);
    }

    // softmax: rows t0=4hi+i (s=lo valid iff lo<=4hi+i), t1=16+4hi+i (a10 all valid, a11 iff lo<=4hi+i)
#pragma unroll
    for (int i = 0; i < 4; ++i) {
        bool ok = lo <= 4 * hi + i;
        float v00 = ok ? a00[i] : -1e30f;
        float v10 = a10[i];
        float v11 = ok ? a11[i] : -1e30f;

        float m = v00;
        m = fmaxf(m, __shfl_xor(m, 1)); m = fmaxf(m, __shfl_xor(m, 2));
        m = fmaxf(m, __shfl_xor(m, 4)); m = fmaxf(m, __shfl_xor(m, 8));
        float e = __expf(v00 - m);
        float s = e;
        s += __shfl_xor(s, 1); s += __shfl_xor(s, 2); s += __shfl_xor(s, 4); s += __shfl_xor(s, 8);
        float p00 = e / s;

        float mm = fmaxf(v10, v11);
        mm = fmaxf(mm, __shfl_xor(mm, 1)); mm = fmaxf(mm, __shfl_xor(mm, 2));
        mm = fmaxf(mm, __shfl_xor(mm, 4)); mm = fmaxf(mm, __shfl_xor(mm, 8));
        float e0 = __expf(v10 - mm), e1 = __expf(v11 - mm);
        float ss = e0 + e1;
        ss += __shfl_xor(ss, 1); ss += __shfl_xor(ss, 2); ss += __shfl_xor(ss, 4); ss += __shfl_xor(ss, 8);
        float inv = 1.0f / ss;

        *(unsigned short*)(pb + (4 * hi + i) * 64 + lo * 2) = f2bf(p00);
        *(unsigned short*)(pb + (16 + 4 * hi + i) * 64 + lo * 2) = f2bf(e0 * inv);
        *(unsigned short*)(pb + (16 + 4 * hi + i) * 64 + 32 + lo * 2) = f2bf(e1 * inv);
    }

    // P A-frags: lane(m=lo -> t=tt*16+lo, k=hi*8+j -> s)
    bf16x8 pf0 = *(const bf16x8*)(pb + (size_t)lo * 64 + hi * 16);
    bf16x8 pf1 = *(const bf16x8*)(pb + (size_t)(16 + lo) * 64 + hi * 16);

    unsigned short* oabase = OA + (size_t)pix * 16384;
#pragma unroll 4
    for (int ot = 0; ot < 32; ++ot) {
        bf16x8 uf = *(const bf16x8*)(UT + (size_t)(ot * 16 + lo) * 131072 + (size_t)pix * 32 + hi * 8);
        f32x4 o0 = __builtin_amdgcn_mfma_f32_16x16x32_bf16(pf0, uf, fzero(), 0, 0, 0);
        f32x4 o1 = __builtin_amdgcn_mfma_f32_16x16x32_bf16(pf1, uf, fzero(), 0, 0, 0);
        int o = ot * 16 + lo;
        i32x2 pk0; pk0[0] = pack2(o0[0], o0[1]); pk0[1] = pack2(o0[2], o0[3]);
        i32x2 pk1; pk1[0] = pack2(o1[0], o1[1]); pk1[1] = pack2(o1[2], o1[3]);
        *(i32x2*)(oabase + (size_t)o * 32 + 4 * hi) = pk0;
        *(i32x2*)(oabase + (size_t)o * 32 + 16 + 4 * hi) = pk1;
    }
}

// ---------------------------------------------------------------------------
// k_output: out[b][c][t][h][w] = x + OA[pix][c][t]   (transpose back via LDS)
// ---------------------------------------------------------------------------
__global__ __launch_bounds__(512) void k_output(
    const float* __restrict__ x, const unsigned short* __restrict__ OA, float* __restrict__ out)
{
    int bx = blockIdx.x;                  // 4096 = 4*32*32
    int cbk = bx & 31;
    int h = (bx >> 5) & 31;
    int bb = bx >> 10;
    int c0 = cbk * 16;
    int tid = threadIdx.x;
    extern __shared__ char lds[];

#pragma unroll
    for (int it = 0; it < 4; ++it) {
        int chunk = it * 512 + tid;       // 2048 x 16B
        int pix = chunk >> 6;
        int rem = chunk & 63;
        int c = rem >> 2;
        int th = rem & 3;
        size_t pixg = ((size_t)bb * 32 + h) * 32 + pix;
        i32x4 v = *(const i32x4*)(OA + pixg * 16384 + (size_t)(c0 + c) * 32 + th * 8);
        unsigned Kx = ((unsigned)(pix & 31)) << 2;
        unsigned base = (unsigned)(pix * 1024 + c * 64 + th * 16);
        *(unsigned int*)(lds + ((base + 0u) ^ Kx))  = (unsigned int)v[0];
        *(unsigned int*)(lds + ((base + 4u) ^ Kx))  = (unsigned int)v[1];
        *(unsigned int*)(lds + ((base + 8u) ^ Kx))  = (unsigned int)v[2];
        *(unsigned int*)(lds + ((base + 12u) ^ Kx)) = (unsigned int)v[3];
    }
    __syncthreads();
#pragma unroll
    for (int it = 0; it < 8; ++it) {
        int flat4 = it * 512 + tid;       // 4096 float4
        int c = flat4 >> 8;
        int rem = flat4 & 255;
        int t = rem >> 3, w4 = rem & 7;
        size_t gidx = (((size_t)(bb * 512 + c0 + c)) * 32 + t) * 1024 + h * 32 + w4 * 4;
        float4 xv = *(const float4*)(x + gidx);
        float4 ov;
        {
            int pix = w4 * 4 + 0;
            unsigned off = ((unsigned)(pix * 1024 + c * 64 + t * 2)) ^ (((unsigned)(pix & 31)) << 2);
            ov.x = xv.x + bf2f(*(const unsigned short*)(lds + off));
        }
        {
            int pix = w4 * 4 + 1;
            unsigned off = ((unsigned)(pix * 1024 + c * 64 + t * 2)) ^ (((unsigned)(pix & 31)) << 2);
            ov.y = xv.y + bf2f(*(const unsigned short*)(lds + off));
        }
        {
            int pix = w4 * 4 + 2;
            unsigned off = ((unsigned)(pix * 1024 + c * 64 + t * 2)) ^ (((unsigned)(pix & 31)) << 2);
            ov.z = xv.z + bf2f(*(const unsigned short*)(lds + off));
        }
        {
            int pix = w4 * 4 + 3;
            unsigned off = ((unsigned)(pix * 1024 + c * 64 + t * 2)) ^ (((unsigned)(pix & 31)) << 2);
            ov.w = xv.w + bf2f(*(const unsigned short*)(lds + off));
        }
        *(float4*)(out + gidx) = ov;
    }
}

// ---------------------------------------------------------------------------
extern "C" void kernel_launch(void* const* d_in, const int* in_sizes, int n_in,
                              void* d_out, int out_size, void* d_ws, size_t ws_size,
                              hipStream_t stream)
{
    const float* x     = (const float*)d_in[0];
    const float* gamma = (const float*)d_in[1];
    const float* beta  = (const float*)d_in[2];
    const float* wq    = (const float*)d_in[3];
    const float* wk    = (const float*)d_in[4];
    const float* wv    = (const float*)d_in[5];
    const float* wproj = (const float*)d_in[6];
    float* out = (float*)d_out;

    char* ws = (char*)d_ws;
    const size_t OFF_G   = 134217728;             // 128MB Hraw/OA first
    const size_t OFF_UT  = 268435456;
    const size_t OFF_WP  = 402653184;
    const size_t OFF_RSW = OFF_WP + 1048576;
    const size_t OFF_BW  = OFF_RSW + 4096;
    const size_t OFF_SUM = OFF_BW + 4096;
    const size_t OFF_MR  = OFF_SUM + 1024;

    unsigned short* Hbuf = (unsigned short*)ws;               // Hraw, then OA in-place
    unsigned short* Gb   = (unsigned short*)(ws + OFF_G);     // G[n][512]
    unsigned short* UTb  = (unsigned short*)(ws + OFF_UT);    // UT[512][n]
    unsigned short* Wp   = (unsigned short*)(ws + OFF_WP);    // W'[1024][512]
    float* rsW  = (float*)(ws + OFF_RSW);
    float* bW   = (float*)(ws + OFF_BW);
    float* sums = (float*)(ws + OFF_SUM);
    float* mr   = (float*)(ws + OFF_MR);

    hipMemsetAsync(rsW, 0, 8192, stream);                     // rsW + bW
    hipMemsetAsync(sums, 0, 1024, stream);

    hipFuncSetAttribute((const void*)k_transpose_stats, hipFuncAttributeMaxDynamicSharedMemorySize, 65536 + 128);
    hipFuncSetAttribute((const void*)k_gemm, hipFuncAttributeMaxDynamicSharedMemorySize, 65536);

    kw_weights<<<dim3(128), dim3(256), 0, stream>>>(wq, wk, wproj, wv, gamma, beta, Wp, rsW, bW);
    k_transpose_stats<<<dim3(2048), dim3(512), 65536 + 128, stream>>>(x, Hbuf, sums);
    k_finalize<<<dim3(1), dim3(128), 0, stream>>>(sums, mr);
    k_gemm<<<dim3(4096), dim3(512), 65536, stream>>>(Hbuf, Wp, rsW, bW, mr, Gb, UTb);
    k_attn<<<dim3(512), dim3(512), 0, stream>>>(Hbuf, Gb, UTb, gamma, beta, mr, Hbuf);
    k_output<<<dim3(4096), dim3(512), 32768, stream>>>(x, Hbuf, out);
}

// Round 8
// 1591.042 us; speedup vs baseline: 1.0263x; 1.0263x over previous
//
#include <hip/hip_runtime.h>
#include <hip/hip_bf16.h>

typedef __attribute__((ext_vector_type(4))) float f32x4;
typedef __attribute__((ext_vector_type(8))) short bf16x8;   // MFMA 16x16x32 A/B operand
typedef __attribute__((ext_vector_type(4))) int   i32x4;
typedef __attribute__((ext_vector_type(2))) int   i32x2;

#define QK_SCALE 0.04419417382415922f   // 512^-0.5

static __device__ __forceinline__ unsigned short f2bf(float f) {
    unsigned int u = __builtin_bit_cast(unsigned int, f);
    u += 0x7fffu + ((u >> 16) & 1u);          // RNE
    return (unsigned short)(u >> 16);
}
static __device__ __forceinline__ float bf2f(unsigned short h) {
    unsigned int u = ((unsigned int)h) << 16;
    return __builtin_bit_cast(float, u);
}
static __device__ __forceinline__ f32x4 fzero() {
    f32x4 v; v[0] = 0.f; v[1] = 0.f; v[2] = 0.f; v[3] = 0.f; return v;
}
static __device__ __forceinline__ int pack2(float a, float b) {
    return (int)((((unsigned)f2bf(b)) << 16) | f2bf(a));
}

// ---------------------------------------------------------------------------
// kw_weights: W'[0:512]   = (wq^T wk) * gamma[c] * QK_SCALE   (G weights)
//             W'[512:1024]= (wproj wv) * gamma[c]             (U weights)
// rsW[o] = sum_c W'[o][c];  bW[o] = sum_c W0[o][c]*beta[c]
// ---------------------------------------------------------------------------
__global__ __launch_bounds__(256) void kw_weights(
    const float* __restrict__ wq, const float* __restrict__ wk,
    const float* __restrict__ wproj, const float* __restrict__ wv,
    const float* __restrict__ gamma, const float* __restrict__ beta,
    unsigned short* __restrict__ Wp, float* __restrict__ rsW, float* __restrict__ bW)
{
    int bx = blockIdx.x;            // 128 blocks: [0,64) -> G, [64,128) -> U
    int mat = bx >> 6;
    int tile = bx & 63;
    int i0 = (tile >> 3) * 64, j0 = (tile & 7) * 64;
    const float* A  = mat ? wproj : wq;
    const float* Bm = mat ? wv : wk;
    __shared__ float At[16][64];
    __shared__ float Bt[16][64];
    int tid = threadIdx.x;
    int ty = tid >> 4, tx = tid & 15;
    float acc[4][4] = {};
    for (int k0 = 0; k0 < 512; k0 += 16) {
        if (mat == 0) {
            // At[kk][ii] = wq[k0+kk][i0+ii]   (wq^T form)
#pragma unroll
            for (int r = 0; r < 4; ++r) {
                int idx = r * 256 + tid;
                At[idx >> 6][idx & 63] = A[(size_t)(k0 + (idx >> 6)) * 512 + i0 + (idx & 63)];
            }
        } else {
            // At[kk][ii] = wproj[i0+ii][k0+kk]
#pragma unroll
            for (int r = 0; r < 4; ++r) {
                int idx = r * 256 + tid;
                At[idx & 15][idx >> 4] = A[(size_t)(i0 + (idx >> 4)) * 512 + k0 + (idx & 15)];
            }
        }
#pragma unroll
        for (int r = 0; r < 4; ++r) {
            int idx = r * 256 + tid;
            Bt[idx >> 6][idx & 63] = Bm[(size_t)(k0 + (idx >> 6)) * 512 + j0 + (idx & 63)];
        }
        __syncthreads();
#pragma unroll
        for (int kk = 0; kk < 16; ++kk)
#pragma unroll
            for (int i = 0; i < 4; ++i)
#pragma unroll
                for (int j = 0; j < 4; ++j)
                    acc[i][j] += At[kk][ty * 4 + i] * Bt[kk][tx * 4 + j];
        __syncthreads();
    }
    float sc = mat ? 1.0f : QK_SCALE;
#pragma unroll
    for (int i = 0; i < 4; ++i) {
        int o = mat * 512 + i0 + ty * 4 + i;
        float rsum = 0.f, bsum = 0.f;
        ushort4 pk;
        unsigned short e[4];
#pragma unroll
        for (int j = 0; j < 4; ++j) {
            int c = j0 + tx * 4 + j;
            float w0 = acc[i][j] * sc;
            float wg = w0 * gamma[c];
            rsum += wg;
            bsum += w0 * beta[c];
            e[j] = f2bf(wg);
        }
        pk.x = e[0]; pk.y = e[1]; pk.z = e[2]; pk.w = e[3];
        *(ushort4*)(Wp + (size_t)o * 512 + j0 + tx * 4) = pk;
        // reduce rsum/bsum across tx (16 lanes, same ty)
        rsum += __shfl_xor(rsum, 1); bsum += __shfl_xor(bsum, 1);
        rsum += __shfl_xor(rsum, 2); bsum += __shfl_xor(bsum, 2);
        rsum += __shfl_xor(rsum, 4); bsum += __shfl_xor(bsum, 4);
        rsum += __shfl_xor(rsum, 8); bsum += __shfl_xor(bsum, 8);
        if (tx == 0) { atomicAdd(&rsW[o], rsum); atomicAdd(&bW[o], bsum); }
    }
}

// ---------------------------------------------------------------------------
// k_transpose_stats: x[b][c][t][h][w] -> Hraw[pix][t][c] (raw bf16)
// + per-(b,t) partial sums (sum, sumsq) via atomics.
// ---------------------------------------------------------------------------
__global__ __launch_bounds__(512) void k_transpose_stats(
    const float* __restrict__ x, unsigned short* __restrict__ Hraw, float* __restrict__ sums)
{
    int bx = blockIdx.x;                  // 2048 = 4*32*16
    int tp = bx & 15;
    int h  = (bx >> 4) & 31;
    int bb = bx >> 9;
    int t0 = tp * 2;
    int tid = threadIdx.x;
    extern __shared__ char lds[];         // 64KB + 128B reduce scratch
    float* red = (float*)(lds + 65536);

    int tt = (tid >> 3) & 1;
    int w4 = tid & 7;
    int cb = tid >> 4;
    float s = 0.f, q = 0.f;
    const unsigned int Kt = (unsigned int)tt * 64u + (unsigned int)w4 * 8u;
#pragma unroll
    for (int it = 0; it < 16; ++it) {
        int c = it * 32 + cb;
        float4 v = *(const float4*)(x + (((size_t)(bb * 512 + c)) * 32 + (t0 + tt)) * 1024 + h * 32 + w4 * 4);
        s += v.x + v.y + v.z + v.w;
        q += v.x * v.x + v.y * v.y + v.z * v.z + v.w * v.w;
        unsigned int p0 = ((unsigned int)f2bf(v.y) << 16) | f2bf(v.x);
        unsigned int p1 = ((unsigned int)f2bf(v.w) << 16) | f2bf(v.z);
        unsigned int Kx = ((unsigned int)((c >> 3) & 31)) << 2;
        unsigned int base = (unsigned int)c * 128u + Kt;
        *(unsigned int*)(lds + ((base + 0u) ^ Kx)) = p0;
        *(unsigned int*)(lds + ((base + 4u) ^ Kx)) = p1;
    }
    s += __shfl_xor(s, 1);  q += __shfl_xor(q, 1);
    s += __shfl_xor(s, 2);  q += __shfl_xor(q, 2);
    s += __shfl_xor(s, 4);  q += __shfl_xor(q, 4);
    s += __shfl_xor(s, 16); q += __shfl_xor(q, 16);
    s += __shfl_xor(s, 32); q += __shfl_xor(q, 32);
    int wid = tid >> 6, lane = tid & 63;
    if (lane == 0) { red[wid * 4 + 0] = s; red[wid * 4 + 1] = q; }
    if (lane == 8) { red[wid * 4 + 2] = s; red[wid * 4 + 3] = q; }
    __syncthreads();
    if (tid < 4) {
        float a = 0.f;
#pragma unroll
        for (int w = 0; w < 8; ++w) a += red[w * 4 + tid];
        int f = bb * 32 + t0 + (tid >> 1);
        atomicAdd(&sums[f * 2 + (tid & 1)], a);
    }
#pragma unroll
    for (int rnd = 0; rnd < 8; ++rnd) {
        int row = rnd * 8 + wid;
        int w = row >> 1, ttw = row & 1;
        int c0 = lane * 8;
        unsigned short e[8];
#pragma unroll
        for (int j = 0; j < 8; ++j) {
            int c = c0 + j;
            unsigned int Kx = ((unsigned int)((c >> 3) & 31)) << 2;
            unsigned int off = ((unsigned int)(c * 128 + ttw * 64 + 2 * w)) ^ Kx;
            e[j] = *(const unsigned short*)(lds + off);
        }
        i32x4 ov;
        ov[0] = (int)(((unsigned int)e[1] << 16) | e[0]);
        ov[1] = (int)(((unsigned int)e[3] << 16) | e[2]);
        ov[2] = (int)(((unsigned int)e[5] << 16) | e[4]);
        ov[3] = (int)(((unsigned int)e[7] << 16) | e[6]);
        size_t pix = ((size_t)bb * 32 + h) * 32 + w;
        *(i32x4*)(Hraw + pix * 16384 + (size_t)(t0 + ttw) * 512 + c0) = ov;
    }
}

// ---------------------------------------------------------------------------
__global__ void k_finalize(const float* __restrict__ sums, float* __restrict__ mr) {
    int f = threadIdx.x;                  // 128 frames
    float mean = sums[f * 2] * (1.f / 524288.f);
    float var  = sums[f * 2 + 1] * (1.f / 524288.f) - mean * mean;
    mr[f * 2]     = mean;
    mr[f * 2 + 1] = rsqrtf(var + 1e-6f);
}

// ---------------------------------------------------------------------------
// k_gemm: D[1024 o][131072 n] = W'[o][c] . Hraw[n][c]  (K=512), epilogue affine:
//   val = rs_n * (D - mu_n * rsW[o]) + bW[o]
// o<512  -> G[n][o]      o>=512 -> UT[o-512][n]
// Tiles: BM=128 (8 mtiles), BN=256 (512 strips), BK=64 dbuf via global_load_lds.
// Epilogue: affine -> bf16 -> swizzled LDS tile (reuses staging buffer) ->
// full-cache-line coalesced stores (R6 had 12x write amplification from 8B
// scattered stores; R7 had an OOB rsW/bW read from a double +512 offset).
// ---------------------------------------------------------------------------
__global__ __launch_bounds__(512, 4) void k_gemm(
    const unsigned short* __restrict__ Hraw,
    const unsigned short* __restrict__ Wp,
    const float* __restrict__ rsW, const float* __restrict__ bW,
    const float* __restrict__ mr,
    unsigned short* __restrict__ G, unsigned short* __restrict__ UT)
{
    extern __shared__ char lds[];
    int d = blockIdx.x;
    int mtile = (d >> 3) & 7;
    int strip = (d & 7) | ((d >> 6) << 3);
    int n0 = strip * 256;
    int tid = threadIdx.x, wid = tid >> 6, lane = tid & 63;
    int lo = lane & 15, hi = lane >> 4;
    int o0w = mtile * 128 + (wid >> 2) * 64;
    int n0w = (wid & 3) * 64;
    bool isU = mtile >= 4;

    int srow = tid >> 3;                                    // 0..63
    unsigned scol = (((unsigned)(tid & 7)) * 16u) ^ ((((unsigned)srow) & 7u) << 4);

    f32x4 acc[4][4];
#pragma unroll
    for (int a = 0; a < 4; ++a)
#pragma unroll
        for (int b = 0; b < 4; ++b) acc[a][b] = fzero();

#define STAGE(bufi, kk)                                                                                   \
    {                                                                                                     \
        _Pragma("unroll")                                                                                 \
        for (int r = 0; r < 4; ++r) {                                                                     \
            const char* src = (const char*)Hraw + (size_t)(n0 + r * 64 + srow) * 1024 + (size_t)(kk) * 128 + scol; \
            char* dst = lds + (bufi) * 32768 + r * 8192 + wid * 1024;                                     \
            __builtin_amdgcn_global_load_lds((const __attribute__((address_space(1))) unsigned int*)src,  \
                                             (__attribute__((address_space(3))) unsigned int*)dst, 16, 0, 0); \
        }                                                                                                 \
    }

    STAGE(0, 0);
    __syncthreads();

    const unsigned short* wbase = Wp + (size_t)(o0w + lo) * 512 + hi * 8;
    int buf = 0;
    for (int k = 0; k < 8; ++k) {
        if (k < 7) STAGE(buf ^ 1, k + 1);
        const char* B = lds + buf * 32768;
#pragma unroll
        for (int half = 0; half < 2; ++half) {
            bf16x8 wa[4], hb[4];
#pragma unroll
            for (int mt = 0; mt < 4; ++mt)
                wa[mt] = *(const bf16x8*)(wbase + (size_t)mt * 16 * 512 + k * 64 + half * 32);
#pragma unroll
            for (int nt = 0; nt < 4; ++nt) {
                int n = n0w + nt * 16 + lo;
                unsigned off = (unsigned)(n * 128) + (((unsigned)(half * 64 + hi * 16)) ^ ((((unsigned)n) & 7u) << 4));
                hb[nt] = *(const bf16x8*)(B + off);
            }
            if (!isU) {
#pragma unroll
                for (int mt = 0; mt < 4; ++mt)
#pragma unroll
                    for (int nt = 0; nt < 4; ++nt)
                        acc[mt][nt] = __builtin_amdgcn_mfma_f32_16x16x32_bf16(wa[mt], hb[nt], acc[mt][nt], 0, 0, 0);
            } else {
#pragma unroll
                for (int mt = 0; mt < 4; ++mt)
#pragma unroll
                    for (int nt = 0; nt < 4; ++nt)
                        acc[mt][nt] = __builtin_amdgcn_mfma_f32_16x16x32_bf16(hb[nt], wa[mt], acc[mt][nt], 0, 0, 0);
            }
        }
        __syncthreads();
        buf ^= 1;
    }
#undef STAGE

    // ---- epilogue: affine -> bf16 -> swizzled LDS tile -> coalesced stores ----
    // (staging buffers are dead after the final barrier above)
    if (!isU) {
        // acc: row(4hi+i)=o-rel, col(lo)=n-rel. LDS tile: [n_rel 256][o_rel 128] bf16,
        // byte = n*256 + (o*2 ^ ((n&15)<<4)).
#pragma unroll
        for (int nt = 0; nt < 4; ++nt) {
            int n_rel = n0w + nt * 16 + lo;
            int n = n0 + n_rel;
            int f = ((n >> 15) << 5) | (n & 31);
            float2 mv = *(const float2*)(mr + f * 2);
#pragma unroll
            for (int mt = 0; mt < 4; ++mt) {
                int ob_rel = (wid >> 2) * 64 + mt * 16 + 4 * hi;
                int ob = mtile * 128 + ob_rel;
                f32x4 rw = *(const f32x4*)(rsW + ob);
                f32x4 bv = *(const f32x4*)(bW + ob);
                f32x4 a = acc[mt][nt];
                i32x2 pk;
                pk[0] = pack2(mv.y * (a[0] - mv.x * rw[0]) + bv[0],
                              mv.y * (a[1] - mv.x * rw[1]) + bv[1]);
                pk[1] = pack2(mv.y * (a[2] - mv.x * rw[2]) + bv[2],
                              mv.y * (a[3] - mv.x * rw[3]) + bv[3]);
                unsigned byte = (unsigned)(n_rel * 256) + (((unsigned)(ob_rel * 2)) ^ (((unsigned)(n_rel & 15)) << 4));
                *(i32x2*)(lds + byte) = pk;
            }
        }
        __syncthreads();
#pragma unroll
        for (int it = 0; it < 8; ++it) {
            int idx = it * 512 + tid;
            int row = idx >> 4, ccol = idx & 15;
            unsigned byte = (unsigned)(row * 256) + (((unsigned)(ccol * 16)) ^ (((unsigned)(row & 15)) << 4));
            i32x4 v = *(const i32x4*)(lds + byte);
            *(i32x4*)(G + (size_t)(n0 + row) * 512 + mtile * 128 + ccol * 8) = v;
        }
    } else {
        // acc: row(4hi+i)=n-rel, col(lo)=o-rel. LDS tile: [o_rel 128][n_rel 256] bf16,
        // byte = o*512 + (n*2 ^ ((o&31)<<4)).
#pragma unroll
        for (int nt = 0; nt < 4; ++nt) {
            int n_rel4 = n0w + nt * 16 + 4 * hi;     // 4 consecutive n
            float2 mv[4];
#pragma unroll
            for (int i = 0; i < 4; ++i) {
                int n = n0 + n_rel4 + i;
                int f = ((n >> 15) << 5) | (n & 31);
                mv[i] = *(const float2*)(mr + f * 2);
            }
#pragma unroll
            for (int mt = 0; mt < 4; ++mt) {
                int o_rel = (wid >> 2) * 64 + mt * 16 + lo;
                int o = mtile * 128 + o_rel;         // global W' row (mtile>=4 -> already 512..1023)
                float rw = rsW[o], bv = bW[o];
                f32x4 a = acc[mt][nt];
                i32x2 pk;
                pk[0] = pack2(mv[0].y * (a[0] - mv[0].x * rw) + bv,
                              mv[1].y * (a[1] - mv[1].x * rw) + bv);
                pk[1] = pack2(mv[2].y * (a[2] - mv[2].x * rw) + bv,
                              mv[3].y * (a[3] - mv[3].x * rw) + bv);
                unsigned byte = (unsigned)(o_rel * 512) + (((unsigned)(n_rel4 * 2)) ^ (((unsigned)(o_rel & 31)) << 4));
                *(i32x2*)(lds + byte) = pk;
            }
        }
        __syncthreads();
#pragma unroll
        for (int it = 0; it < 8; ++it) {
            int idx = it * 512 + tid;
            int row = idx >> 5, ccol = idx & 31;
            unsigned byte = (unsigned)(row * 512) + (((unsigned)(ccol * 16)) ^ (((unsigned)(row & 31)) << 4));
            i32x4 v = *(const i32x4*)(lds + byte);
            *(i32x4*)(UT + (size_t)((mtile - 4) * 128 + row) * 131072 + n0 + ccol * 8) = v;
        }
    }
}

// ---------------------------------------------------------------------------
// k_attn: 1 pixel per wave, 8 waves/block, no barriers.
// logits[t][s] = sum_c h[c,t] g[c,s]  (h = affine(Hraw) on the fly, A-frags;
// G rows as B-frags; causal tile [t<16][s>=16] skipped). In-register softmax.
// P staged in 2KB/wave LDS. PV: out[t][o] = P . UT-frags; OA written over Hraw.
// ---------------------------------------------------------------------------
__global__ __launch_bounds__(512, 4) void k_attn(
    const unsigned short* Hraw,
    const unsigned short* __restrict__ G,
    const unsigned short* __restrict__ UT,
    const float* __restrict__ gamma, const float* __restrict__ beta,
    const float* __restrict__ mr,
    unsigned short* OA)
{
    __shared__ char plds[16384];
    int tid = threadIdx.x, wid = tid >> 6, lane = tid & 63;
    int lo = lane & 15, hi = lane >> 4;
    int pix = blockIdx.x * 8 + wid;
    int b_ = pix >> 10;
    char* pb = plds + wid * 2048;

    // zero P region (masked slots must read as 0)
    {
        i32x4 z; z[0] = 0; z[1] = 0; z[2] = 0; z[3] = 0;
        *(i32x4*)(pb + lane * 32) = z;
        *(i32x4*)(pb + lane * 32 + 16) = z;
    }

    float2 q0 = *(const float2*)(mr + ((size_t)b_ * 32 + lo) * 2);        // t = lo
    float2 q1 = *(const float2*)(mr + ((size_t)b_ * 32 + 16 + lo) * 2);   // t = 16+lo

    const unsigned short* Hrow0 = Hraw + ((size_t)pix * 32 + lo) * 512;
    const unsigned short* Hrow1 = Hrow0 + 16 * 512;
    const unsigned short* Grow0 = G + ((size_t)pix * 32 + lo) * 512;
    const unsigned short* Grow1 = Grow0 + 16 * 512;

    f32x4 a00 = fzero(), a10 = fzero(), a11 = fzero();
#pragma unroll 2
    for (int c0 = 0; c0 < 512; c0 += 32) {
        int cb = c0 + hi * 8;
        f32x4 g0 = *(const f32x4*)(gamma + cb);
        f32x4 g1 = *(const f32x4*)(gamma + cb + 4);
        f32x4 b0 = *(const f32x4*)(beta + cb);
        f32x4 b1 = *(const f32x4*)(beta + cb + 4);
        bf16x8 r0 = *(const bf16x8*)(Hrow0 + cb);
        bf16x8 r1 = *(const bf16x8*)(Hrow1 + cb);
        bf16x8 gb0 = *(const bf16x8*)(Grow0 + cb);
        bf16x8 gb1 = *(const bf16x8*)(Grow1 + cb);
        bf16x8 h0, h1;
#pragma unroll
        for (int j = 0; j < 8; ++j) {
            float gg = (j < 4) ? g0[j] : g1[j - 4];
            float bb = (j < 4) ? b0[j] : b1[j - 4];
            float x0 = bf2f((unsigned short)r0[j]);
            float x1 = bf2f((unsigned short)r1[j]);
            h0[j] = (short)f2bf((x0 - q0.x) * (q0.y * gg) + bb);
            h1[j] = (short)f2bf((x1 - q1.x) * (q1.y * gg) + bb);
        }
        a00 = __builtin_amdgcn_mfma_f32_16x16x32_bf16(h0, gb0, a00, 0, 0, 0);
        a10 = __builtin_amdgcn_mfma_f32_16x16x32_bf16(h1, gb0, a10, 0, 0, 0);
        a11 = __builtin_amdgcn_mfma_f32_16x16x32_bf16(h1, gb1, a11, 0, 0, 0);
    }

    // softmax: rows t0=4hi+i (s=lo valid iff lo<=4hi+i), t1=16+4hi+i (a10 all valid, a11 iff lo<=4hi+i)
#pragma unroll
    for (int i = 0; i < 4; ++i) {
        bool ok = lo <= 4 * hi + i;
        float v00 = ok ? a00[i] : -1e30f;
        float v10 = a10[i];
        float v11 = ok ? a11[i] : -1e30f;

        float m = v00;
        m = fmaxf(m, __shfl_xor(m, 1)); m = fmaxf(m, __shfl_xor(m, 2));
        m = fmaxf(m, __shfl_xor(m, 4)); m = fmaxf(m, __shfl_xor(m, 8));
        float e = __expf(v00 - m);
        float s = e;
        s += __shfl_xor(s, 1); s += __shfl_xor(s, 2); s += __shfl_xor(s, 4); s += __shfl_xor(s, 8);
        float p00 = e / s;

        float mm = fmaxf(v10, v11);
        mm = fmaxf(mm, __shfl_xor(mm, 1)); mm = fmaxf(mm, __shfl_xor(mm, 2));
        mm = fmaxf(mm, __shfl_xor(mm, 4)); mm = fmaxf(mm, __shfl_xor(mm, 8));
        float e0 = __expf(v10 - mm), e1 = __expf(v11 - mm);
        float ss = e0 + e1;
        ss += __shfl_xor(ss, 1); ss += __shfl_xor(ss, 2); ss += __shfl_xor(ss, 4); ss += __shfl_xor(ss, 8);
        float inv = 1.0f / ss;

        *(unsigned short*)(pb + (4 * hi + i) * 64 + lo * 2) = f2bf(p00);
        *(unsigned short*)(pb + (16 + 4 * hi + i) * 64 + lo * 2) = f2bf(e0 * inv);
        *(unsigned short*)(pb + (16 + 4 * hi + i) * 64 + 32 + lo * 2) = f2bf(e1 * inv);
    }

    // P A-frags: lane(m=lo -> t=tt*16+lo, k=hi*8+j -> s)
    bf16x8 pf0 = *(const bf16x8*)(pb + (size_t)lo * 64 + hi * 16);
    bf16x8 pf1 = *(const bf16x8*)(pb + (size_t)(16 + lo) * 64 + hi * 16);

    unsigned short* oabase = OA + (size_t)pix * 16384;
#pragma unroll 4
    for (int ot = 0; ot < 32; ++ot) {
        bf16x8 uf = *(const bf16x8*)(UT + (size_t)(ot * 16 + lo) * 131072 + (size_t)pix * 32 + hi * 8);
        f32x4 o0 = __builtin_amdgcn_mfma_f32_16x16x32_bf16(pf0, uf, fzero(), 0, 0, 0);
        f32x4 o1 = __builtin_amdgcn_mfma_f32_16x16x32_bf16(pf1, uf, fzero(), 0, 0, 0);
        int o = ot * 16 + lo;
        i32x2 pk0; pk0[0] = pack2(o0[0], o0[1]); pk0[1] = pack2(o0[2], o0[3]);
        i32x2 pk1; pk1[0] = pack2(o1[0], o1[1]); pk1[1] = pack2(o1[2], o1[3]);
        *(i32x2*)(oabase + (size_t)o * 32 + 4 * hi) = pk0;
        *(i32x2*)(oabase + (size_t)o * 32 + 16 + 4 * hi) = pk1;
    }
}

// ---------------------------------------------------------------------------
// k_output: out[b][c][t][h][w] = x + OA[pix][c][t]   (transpose back via LDS)
// ---------------------------------------------------------------------------
__global__ __launch_bounds__(512) void k_output(
    const float* __restrict__ x, const unsigned short* __restrict__ OA, float* __restrict__ out)
{
    int bx = blockIdx.x;                  // 4096 = 4*32*32
    int cbk = bx & 31;
    int h = (bx >> 5) & 31;
    int bb = bx >> 10;
    int c0 = cbk * 16;
    int tid = threadIdx.x;
    extern __shared__ char lds[];

#pragma unroll
    for (int it = 0; it < 4; ++it) {
        int chunk = it * 512 + tid;       // 2048 x 16B
        int pix = chunk >> 6;
        int rem = chunk & 63;
        int c = rem >> 2;
        int th = rem & 3;
        size_t pixg = ((size_t)bb * 32 + h) * 32 + pix;
        i32x4 v = *(const i32x4*)(OA + pixg * 16384 + (size_t)(c0 + c) * 32 + th * 8);
        unsigned Kx = ((unsigned)(pix & 31)) << 2;
        unsigned base = (unsigned)(pix * 1024 + c * 64 + th * 16);
        *(unsigned int*)(lds + ((base + 0u) ^ Kx))  = (unsigned int)v[0];
        *(unsigned int*)(lds + ((base + 4u) ^ Kx))  = (unsigned int)v[1];
        *(unsigned int*)(lds + ((base + 8u) ^ Kx))  = (unsigned int)v[2];
        *(unsigned int*)(lds + ((base + 12u) ^ Kx)) = (unsigned int)v[3];
    }
    __syncthreads();
#pragma unroll
    for (int it = 0; it < 8; ++it) {
        int flat4 = it * 512 + tid;       // 4096 float4
        int c = flat4 >> 8;
        int rem = flat4 & 255;
        int t = rem >> 3, w4 = rem & 7;
        size_t gidx = (((size_t)(bb * 512 + c0 + c)) * 32 + t) * 1024 + h * 32 + w4 * 4;
        float4 xv = *(const float4*)(x + gidx);
        float4 ov;
        {
            int pix = w4 * 4 + 0;
            unsigned off = ((unsigned)(pix * 1024 + c * 64 + t * 2)) ^ (((unsigned)(pix & 31)) << 2);
            ov.x = xv.x + bf2f(*(const unsigned short*)(lds + off));
        }
        {
            int pix = w4 * 4 + 1;
            unsigned off = ((unsigned)(pix * 1024 + c * 64 + t * 2)) ^ (((unsigned)(pix & 31)) << 2);
            ov.y = xv.y + bf2f(*(const unsigned short*)(lds + off));
        }
        {
            int pix = w4 * 4 + 2;
            unsigned off = ((unsigned)(pix * 1024 + c * 64 + t * 2)) ^ (((unsigned)(pix & 31)) << 2);
            ov.z = xv.z + bf2f(*(const unsigned short*)(lds + off));
        }
        {
            int pix = w4 * 4 + 3;
            unsigned off = ((unsigned)(pix * 1024 + c * 64 + t * 2)) ^ (((unsigned)(pix & 31)) << 2);
            ov.w = xv.w + bf2f(*(const unsigned short*)(lds + off));
        }
        *(float4*)(out + gidx) = ov;
    }
}

// ---------------------------------------------------------------------------
extern "C" void kernel_launch(void* const* d_in, const int* in_sizes, int n_in,
                              void* d_out, int out_size, void* d_ws, size_t ws_size,
                              hipStream_t stream)
{
    const float* x     = (const float*)d_in[0];
    const float* gamma = (const float*)d_in[1];
    const float* beta  = (const float*)d_in[2];
    const float* wq    = (const float*)d_in[3];
    const float* wk    = (const float*)d_in[4];
    const float* wv    = (const float*)d_in[5];
    const float* wproj = (const float*)d_in[6];
    float* out = (float*)d_out;

    char* ws = (char*)d_ws;
    const size_t OFF_G   = 134217728;             // 128MB Hraw/OA first
    const size_t OFF_UT  = 268435456;
    const size_t OFF_WP  = 402653184;
    const size_t OFF_RSW = OFF_WP + 1048576;
    const size_t OFF_BW  = OFF_RSW + 4096;
    const size_t OFF_SUM = OFF_BW + 4096;
    const size_t OFF_MR  = OFF_SUM + 1024;

    unsigned short* Hbuf = (unsigned short*)ws;               // Hraw, then OA in-place
    unsigned short* Gb   = (unsigned short*)(ws + OFF_G);     // G[n][512]
    unsigned short* UTb  = (unsigned short*)(ws + OFF_UT);    // UT[512][n]
    unsigned short* Wp   = (unsigned short*)(ws + OFF_WP);    // W'[1024][512]
    float* rsW  = (float*)(ws + OFF_RSW);
    float* bW   = (float*)(ws + OFF_BW);
    float* sums = (float*)(ws + OFF_SUM);
    float* mr   = (float*)(ws + OFF_MR);

    hipMemsetAsync(rsW, 0, 8192, stream);                     // rsW + bW
    hipMemsetAsync(sums, 0, 1024, stream);

    hipFuncSetAttribute((const void*)k_transpose_stats, hipFuncAttributeMaxDynamicSharedMemorySize, 65536 + 128);
    hipFuncSetAttribute((const void*)k_gemm, hipFuncAttributeMaxDynamicSharedMemorySize, 65536);

    kw_weights<<<dim3(128), dim3(256), 0, stream>>>(wq, wk, wproj, wv, gamma, beta, Wp, rsW, bW);
    k_transpose_stats<<<dim3(2048), dim3(512), 65536 + 128, stream>>>(x, Hbuf, sums);
    k_finalize<<<dim3(1), dim3(128), 0, stream>>>(sums, mr);
    k_gemm<<<dim3(4096), dim3(512), 65536, stream>>>(Hbuf, Wp, rsW, bW, mr, Gb, UTb);
    k_attn<<<dim3(512), dim3(512), 0, stream>>>(Hbuf, Gb, UTb, gamma, beta, mr, Hbuf);
    k_output<<<dim3(4096), dim3(512), 32768, stream>>>(x, Hbuf, out);
}